// Round 6
// baseline (393.920 us; speedup 1.0000x reference)
//
#include <hip/hip_runtime.h>
#include <hip/hip_bf16.h>
#include <math.h>

// B=16, F=4096, Q=64, DIM=512, H=8, DH=64, MULT=2
typedef short bf16x8 __attribute__((ext_vector_type(8)));
typedef float f32x4 __attribute__((ext_vector_type(4)));

__device__ __forceinline__ f32x4 mfma16(bf16x8 a, bf16x8 b, f32x4 c) {
    return __builtin_amdgcn_mfma_f32_16x16x32_bf16(a, b, c, 0, 0, 0);
}

// manual fp32 -> bf16 round-to-nearest-even (all values finite here)
__device__ __forceinline__ unsigned short f2b(float f) {
    unsigned int x = __float_as_uint(f);
    unsigned int r = (x + 0x7fffu + ((x >> 16) & 1u)) >> 16;
    return (unsigned short)r;
}

#define GLOBAL_AS(p) ((__attribute__((address_space(1))) void*)(p))
#define LDS_AS(p)    ((__attribute__((address_space(3))) void*)(p))

// ---------------- mask compaction: PARALLEL two-phase ballot + LDS scan -----------
__global__ __launch_bounds__(1024) void mask_compact(const int* __restrict__ mask,
                                                     int* __restrict__ cidx,
                                                     int* __restrict__ cntp) {
    __shared__ unsigned long long bals[64];
    __shared__ int base[64];
    int b = blockIdx.x;
    int tid = threadIdx.x;
    int wave = tid >> 6, lane = tid & 63;
    const int* mb = mask + b * 4096;
#pragma unroll
    for (int k = 0; k < 4; ++k) {
        int g = wave * 4 + k;
        int m = mb[g * 64 + lane] != 0;
        unsigned long long bal = __ballot(m);
        if (lane == 0) bals[g] = bal;
    }
    __syncthreads();
    if (wave == 0) {
        int v = __popcll(bals[lane]);
        int own = v;
#pragma unroll
        for (int off = 1; off < 64; off <<= 1) {
            int n = __shfl_up(v, off);
            if (lane >= off) v += n;
        }
        base[lane] = v - own;          // exclusive prefix
        if (lane == 63) {
            cntp[b] = v;
            cntp[16 + b] = (v + 127) & ~127;
        }
    }
    __syncthreads();
#pragma unroll
    for (int k = 0; k < 4; ++k) {
        int g = wave * 4 + k;
        unsigned long long bal = bals[g];
        int m = (int)((bal >> lane) & 1ull);
        int pre = __popcll(bal & ((1ull << lane) - 1ull));
        if (m) cidx[b * 4096 + base[g] + pre] = g * 64 + lane;
    }
}

// ---------------- merged LayerNorm: features (gather+compact) AND latents ---------
// blocks [0,16384): features rows (b*4096+j, gathered); [16384,16640): latent rows.
__global__ __launch_bounds__(256) void ln_all(const float* __restrict__ feat,
                                              const float* __restrict__ lat,
                                              const int* __restrict__ cidx,
                                              const int* __restrict__ cntp,
                                              const float* __restrict__ gf,
                                              const float* __restrict__ bf_,
                                              const float* __restrict__ gl,
                                              const float* __restrict__ bl,
                                              unsigned short* __restrict__ xn,
                                              unsigned short* __restrict__ latn) {
    int bid = blockIdx.x;
    int lane = threadIdx.x & 63;
    const float* rp; unsigned short* orow; const float *gw, *bw;
    if (bid < 16384) {
        int row = bid * 4 + (threadIdx.x >> 6);      // b*4096 + j
        int b = row >> 12, j = row & 4095;
        int cnt = cntp[b], padded = cntp[16 + b];
        if (j >= padded) return;
        orow = xn + (size_t)row * 512;
        if (j >= cnt) {
            ushort4 z; z.x = z.y = z.z = z.w = 0;
            *(ushort4*)(orow + lane * 4) = z;
            *(ushort4*)(orow + 256 + lane * 4) = z;
            return;
        }
        int src = cidx[b * 4096 + j];
        rp = feat + ((size_t)b * 4096 + src) * 512;
        gw = gf; bw = bf_;
    } else {
        int row = (bid - 16384) * 4 + (threadIdx.x >> 6);
        rp = lat + (size_t)row * 512;
        orow = latn + (size_t)row * 512;
        gw = gl; bw = bl;
    }
    float4 x0 = *(const float4*)(rp + lane * 4);
    float4 x1 = *(const float4*)(rp + 256 + lane * 4);
    float s  = x0.x + x0.y + x0.z + x0.w + x1.x + x1.y + x1.z + x1.w;
    float sq = x0.x*x0.x + x0.y*x0.y + x0.z*x0.z + x0.w*x0.w
             + x1.x*x1.x + x1.y*x1.y + x1.z*x1.z + x1.w*x1.w;
#pragma unroll
    for (int m = 1; m < 64; m <<= 1) {
        s  += __shfl_xor(s, m);
        sq += __shfl_xor(sq, m);
    }
    float mean = s * (1.0f / 512.0f);
    float var  = sq * (1.0f / 512.0f) - mean * mean;
    float rs   = rsqrtf(var + 1e-5f);
    float4 g0 = *(const float4*)(gw + lane * 4);
    float4 g1 = *(const float4*)(gw + 256 + lane * 4);
    float4 b0 = *(const float4*)(bw + lane * 4);
    float4 b1 = *(const float4*)(bw + 256 + lane * 4);
    ushort4 o0, o1;
    o0.x = f2b((x0.x - mean) * rs * g0.x + b0.x);
    o0.y = f2b((x0.y - mean) * rs * g0.y + b0.y);
    o0.z = f2b((x0.z - mean) * rs * g0.z + b0.z);
    o0.w = f2b((x0.w - mean) * rs * g0.w + b0.w);
    o1.x = f2b((x1.x - mean) * rs * g1.x + b1.x);
    o1.y = f2b((x1.y - mean) * rs * g1.y + b1.y);
    o1.z = f2b((x1.z - mean) * rs * g1.z + b1.z);
    o1.w = f2b((x1.w - mean) * rs * g1.w + b1.w);
    *(ushort4*)(orow + lane * 4) = o0;
    *(ushort4*)(orow + 256 + lane * 4) = o1;
}

// ---------------- all 5 weight transposes in ONE launch ---------------------------
__global__ __launch_bounds__(256) void transpose_all(const float* __restrict__ Wq,
                                                     const float* __restrict__ Wk,
                                                     const float* __restrict__ Wv,
                                                     const float* __restrict__ W1,
                                                     const float* __restrict__ W2,
                                                     unsigned short* __restrict__ WqT,
                                                     unsigned short* __restrict__ WkT,
                                                     unsigned short* __restrict__ WvT,
                                                     unsigned short* __restrict__ W1T,
                                                     unsigned short* __restrict__ W2T) {
    __shared__ float tile[32][33];
    int id = blockIdx.x;
    const float* in; unsigned short* out; int R, C;
    if (id < 256)       { in = Wq; out = WqT; R = 512;  C = 512;  }
    else if (id < 512)  { in = Wk; out = WkT; R = 512;  C = 512;  id -= 256;  }
    else if (id < 768)  { in = Wv; out = WvT; R = 512;  C = 512;  id -= 512;  }
    else if (id < 1280) { in = W1; out = W1T; R = 512;  C = 1024; id -= 768;  }
    else                { in = W2; out = W2T; R = 1024; C = 512;  id -= 1280; }
    int tilesX = C >> 5;
    int c0 = (id % tilesX) * 32, r0 = (id / tilesX) * 32;
    int tx = threadIdx.x & 31, ty = threadIdx.x >> 5;
#pragma unroll
    for (int i = 0; i < 32; i += 8)
        tile[ty + i][tx] = in[(size_t)(r0 + ty + i) * C + c0 + tx];
    __syncthreads();
#pragma unroll
    for (int i = 0; i < 32; i += 8)
        out[(size_t)(c0 + ty + i) * R + r0 + tx] = f2b(tile[tx][ty + i]);
}

// ---------------- small GEMM, 64x64 tile: C[M,N] = A[M,K] * Bt[N,K]^T --------------
template <int EPI>
__global__ __launch_bounds__(256) void gemm_bt64(const unsigned short* __restrict__ A,
                                                 const unsigned short* __restrict__ Bt,
                                                 void* __restrict__ Cv,
                                                 int M, int N, int K) {
    __shared__ unsigned short As[64 * 32];
    __shared__ unsigned short Bs[64 * 32];
    const int tid = threadIdx.x;
    const int wave = tid >> 6, lane = tid & 63;
    const int qd = lane >> 4, cc = lane & 15;
    const int m0 = blockIdx.y * 64, n0 = blockIdx.x * 64;
    const int wm = (wave >> 1) * 32, wn = (wave & 1) * 32;
    const int lrow = wave * 16 + (lane >> 2);
    const int lcol = (lane & 3) * 8;
    f32x4 acc[2][2] = {};

    for (int kt = 0; kt < K; kt += 32) {
        const unsigned short* ga = A + (size_t)(m0 + lrow) * K + kt + lcol;
        __builtin_amdgcn_global_load_lds(GLOBAL_AS(ga), LDS_AS(&As[wave * 512]), 16, 0, 0);
        const unsigned short* gb = Bt + (size_t)(n0 + lrow) * K + kt + lcol;
        __builtin_amdgcn_global_load_lds(GLOBAL_AS(gb), LDS_AS(&Bs[wave * 512]), 16, 0, 0);
        __syncthreads();
        bf16x8 af[2], bfr[2];
#pragma unroll
        for (int i = 0; i < 2; ++i)
            af[i] = *(const bf16x8*)&As[(wm + i * 16 + cc) * 32 + qd * 8];
#pragma unroll
        for (int j = 0; j < 2; ++j)
            bfr[j] = *(const bf16x8*)&Bs[(wn + j * 16 + cc) * 32 + qd * 8];
#pragma unroll
        for (int i = 0; i < 2; ++i)
#pragma unroll
            for (int j = 0; j < 2; ++j)
                acc[i][j] = mfma16(af[i], bfr[j], acc[i][j]);
        __syncthreads();
    }
#pragma unroll
    for (int i = 0; i < 2; ++i) {
#pragma unroll
        for (int j = 0; j < 2; ++j) {
            int row = m0 + wm + i * 16 + qd * 4;
            int col = n0 + wn + j * 16 + cc;
#pragma unroll
            for (int r = 0; r < 4; ++r) {
                float v = acc[i][j][r];
                if (EPI == 1) v = fmaxf(v, 0.0f);
                if (EPI == 2)
                    ((float*)Cv)[(size_t)(row + r) * N + col] = v;
                else
                    ((unsigned short*)Cv)[(size_t)(row + r) * N + col] = f2b(v);
            }
        }
    }
}

// ---------------- K / V projection, SPLIT: one output tensor per block -------------
// grid = dim3(2048, 2): y==0 -> K blocks, y==1 -> V blocks. Each block = m97-shape
// (16 MFMA + 2 global_load_lds per k-step, 64 acc VGPR, 16 KB LDS) at 3 blocks/CU
// (was fused K+V: 128 acc VGPR -> 2 blocks/CU, latency-exposed). X re-read by the
// V block hits L3 (X totals ~34 MB << 256 MB). Outputs in HEAD-BLOCKED layouts:
//   Khm[b*8+h][f 4096][dh 64]              (a 64-f chunk = 8KB contiguous)
//   Vhm[b*8+h][ftile 64][dh 64][fin 64]    (a 64-f chunk = one 8KB tile)
__global__ __launch_bounds__(256, 3) void gemm_kv(const unsigned short* __restrict__ Xn,
                                                  const unsigned short* __restrict__ WkT,
                                                  const unsigned short* __restrict__ WvT,
                                                  const int* __restrict__ cntp,
                                                  unsigned short* __restrict__ Kout,
                                                  unsigned short* __restrict__ VTout) {
    const int L = blockIdx.x;
    const int kv = blockIdx.y;
    const int t7 = L >> 3;
    const int c = t7 & 3;
    const int m = ((t7 >> 2) << 3) | (L & 7);
    const int m0 = m * 128;
    const int b = m0 >> 12;
    if ((m0 & 4095) >= cntp[16 + b]) return;   // slab fully beyond padded count
    __shared__ unsigned short Xs[128 * 32];
    __shared__ unsigned short Ws[128 * 32];
    const unsigned short* W = kv ? WvT : WkT;
    const int tid = threadIdx.x;
    const int wave = tid >> 6, lane = tid & 63;
    const int qd = lane >> 4, cc = lane & 15;
    const int n0 = c * 128;
    const int wm = (wave >> 1) * 64, wn = (wave & 1) * 64;
    const int lrow = lane >> 2;
    const int lcol = (lane & 3) * 8;
    f32x4 acc[4][4] = {};

    for (int kt = 0; kt < 512; kt += 32) {
#pragma unroll
        for (int r = 0; r < 2; ++r) {
            int slab = wave * 16 + r * 64;
            const unsigned short* gx = Xn + (size_t)(m0 + slab + lrow) * 512 + kt + lcol;
            __builtin_amdgcn_global_load_lds(GLOBAL_AS(gx), LDS_AS(&Xs[slab * 32]), 16, 0, 0);
            const unsigned short* gw = W + (size_t)(n0 + slab + lrow) * 512 + kt + lcol;
            __builtin_amdgcn_global_load_lds(GLOBAL_AS(gw), LDS_AS(&Ws[slab * 32]), 16, 0, 0);
        }
        __syncthreads();
        bf16x8 xf[4], wf[4];
#pragma unroll
        for (int i = 0; i < 4; ++i)
            xf[i] = *(const bf16x8*)&Xs[(wm + i * 16 + cc) * 32 + qd * 8];
#pragma unroll
        for (int j = 0; j < 4; ++j)
            wf[j] = *(const bf16x8*)&Ws[(wn + j * 16 + cc) * 32 + qd * 8];
        if (kv == 0) {
#pragma unroll
            for (int i = 0; i < 4; ++i)
#pragma unroll
                for (int j = 0; j < 4; ++j)
                    acc[i][j] = mfma16(xf[i], wf[j], acc[i][j]);    // rows=f, cols=dh
        } else {
#pragma unroll
            for (int j = 0; j < 4; ++j)
#pragma unroll
                for (int i = 0; i < 4; ++i)
                    acc[j][i] = mfma16(wf[j], xf[i], acc[j][i]);    // rows=dh, cols=f
        }
        __syncthreads();
    }
    if (kv == 0) {
        // K write: rows = compacted f (qd,r), cols = dh-global (cc)
#pragma unroll
        for (int i = 0; i < 4; ++i)
#pragma unroll
            for (int j = 0; j < 4; ++j) {
                int frow = (m0 & 4095) + wm + i * 16 + qd * 4;   // f within batch
                int dhg  = n0 + wn + j * 16 + cc;
                int hh = dhg >> 6, dhl = dhg & 63;
                unsigned short* kp = Kout + ((size_t)(b * 8 + hh) * 4096 + frow) * 64 + dhl;
#pragma unroll
                for (int r = 0; r < 4; ++r)
                    kp[(size_t)r * 64] = f2b(acc[i][j][r]);
            }
    } else {
        // V^T write: rows = dh-global (qd,r), cols = compacted f (cc)
#pragma unroll
        for (int j = 0; j < 4; ++j)
#pragma unroll
            for (int i = 0; i < 4; ++i) {
                int dhg = n0 + wn + j * 16 + qd * 4;
                int fg  = (m0 & 4095) + wm + i * 16 + cc;        // f within batch
                int hh = dhg >> 6, dhl = dhg & 63;
                unsigned short* vp = VTout + (size_t)(b * 8 + hh) * 262144
                                   + (size_t)(fg >> 6) * 4096 + (size_t)dhl * 64 + (fg & 63);
#pragma unroll
                for (int r = 0; r < 4; ++r)
                    vp[(size_t)r * 64] = f2b(acc[j][i][r]);      // r advances dhl
            }
    }
}

// ---------------- fused attention, LDS double-buffered chunk pipeline --------------
// grid = 512: (b, h, fs of 4). Waves SHARE each chunk (wave = q-tile owner qt);
// block walks chunks c = fs, fs+4, ... (~8 chunks) with double-buffered LDS staging
// via global_load_lds (stage c+1 issued before computing c; one barrier per chunk).
// K/V LDS tiles are XOR-swizzled (linear dest + pre-swizzled global source +
// swizzled read) to kill the 16-way stride-128B ds_read_b128 bank conflict.
// Wave-private O accumulation (no cross-wave combine). 18 MFMA/chunk/wave.
__global__ __launch_bounds__(256, 3) void attn_kernel(const unsigned short* __restrict__ Qb,
                                                      const unsigned short* __restrict__ Khm,
                                                      const unsigned short* __restrict__ Vhm,
                                                      const int* __restrict__ cntp,
                                                      float* __restrict__ Opart,
                                                      float* __restrict__ lpart) {
    int blk = blockIdx.x;              // b*32 + h*4 + fs
    int b = blk >> 5;
    int h = (blk >> 2) & 7;
    int fs = blk & 3;
    int cnt = cntp[b];
    int pad = cntp[16 + b];
    int nchunks = pad >> 6;            // 64-f chunks
    int wave = threadIdx.x >> 6, lane = threadIdx.x & 63;
    int qd = lane >> 4, cc = lane & 15;
    const int qt = wave;               // wave owns one 16-q tile

    __shared__ unsigned short Ks[2][64 * 64];     // 2 x 8 KB
    __shared__ unsigned short Vs[2][64 * 64];     // 2 x 8 KB
    __shared__ unsigned short p_lds[4][16][72];   // 9 KB

    const unsigned short* Kbase = Khm + (size_t)(b * 8 + h) * 262144;   // [4096][64]
    const unsigned short* Vbase = Vhm + (size_t)(b * 8 + h) * 262144;   // [64 tiles][64][64]

    // Q fragments for this wave's q-tile (held in registers for the whole kernel)
    const unsigned short* qrow = Qb + (size_t)(b * 64 + qt * 16 + cc) * 512 + h * 64;
    bf16x8 qf0 = *(const bf16x8*)(qrow + qd * 8);
    bf16x8 qf1 = *(const bf16x8*)(qrow + 32 + qd * 8);
    bf16x8 ones;
#pragma unroll
    for (int j = 0; j < 8; ++j) ones[j] = (short)0x3F80;  // bf16 1.0

    f32x4 O4[4] = {};                  // [g]  (dh blocks)
    f32x4 lac = {};
    const float cexp = 0.1803368801f;  // 0.125 * log2(e)

    // stage macro: 16 KB (K 8KB + V 8KB) per chunk; source pre-swizzled so that
    // lds[o] = src[o ^ ((row&7)<<4)], row = o>>7 (involution within each 128B row)
#define STAGE(dst, cidx) do {                                                       \
        const char* kt_ = (const char*)(Kbase + (size_t)(cidx) * 4096);             \
        const char* vt_ = (const char*)(Vbase + (size_t)(cidx) * 4096);             \
        char* kd_ = (char*)&Ks[dst][0];                                             \
        char* vd_ = (char*)&Vs[dst][0];                                             \
        _Pragma("unroll")                                                           \
        for (int i_ = 0; i_ < 2; ++i_) {                                            \
            int o_ = i_ * 4096 + wave * 1024 + lane * 16;                           \
            int sb_ = o_ ^ (((o_ >> 7) & 7) << 4);                                  \
            __builtin_amdgcn_global_load_lds(GLOBAL_AS(kt_ + sb_),                  \
                LDS_AS(kd_ + i_ * 4096 + wave * 1024), 16, 0, 0);                   \
            __builtin_amdgcn_global_load_lds(GLOBAL_AS(vt_ + sb_),                  \
                LDS_AS(vd_ + i_ * 4096 + wave * 1024), 16, 0, 0);                   \
        }                                                                           \
    } while (0)

    int buf = 0;
    if (fs < nchunks) STAGE(0, fs);
    __syncthreads();                   // drains vmcnt -> buf 0 ready

    const int swz = (cc & 7) << 4;
    for (int c = fs; c < nchunks; c += 4) {
        int cn = c + 4;
        if (cn < nchunks) STAGE(buf ^ 1, cn);   // prefetch flies under compute

        const char* ksb = (const char*)&Ks[buf][0];
        const char* vsb = (const char*)&Vs[buf][0];
        int f0 = c * 64;
        bf16x8 kf[4][2], vf[4][2];
        int mv[4];
#pragma unroll
        for (int t = 0; t < 4; ++t) {
            int rb = (t * 16 + cc) * 128;
            kf[t][0] = *(const bf16x8*)(ksb + rb + ((qd << 4) ^ swz));
            kf[t][1] = *(const bf16x8*)(ksb + rb + ((64 + (qd << 4)) ^ swz));
            mv[t] = (f0 + t * 16 + cc) < cnt;
        }
#pragma unroll
        for (int g = 0; g < 4; ++g) {
            int rb = (g * 16 + cc) * 128;
            vf[g][0] = *(const bf16x8*)(vsb + rb + ((qd << 4) ^ swz));
            vf[g][1] = *(const bf16x8*)(vsb + rb + ((64 + (qd << 4)) ^ swz));
        }
        f32x4 s4[4] = {};
#pragma unroll
        for (int t = 0; t < 4; ++t) {
            s4[t] = mfma16(qf0, kf[t][0], s4[t]);
            s4[t] = mfma16(qf1, kf[t][1], s4[t]);
        }
#pragma unroll
        for (int t = 0; t < 4; ++t)
#pragma unroll
            for (int r = 0; r < 4; ++r) {
                float p = mv[t] ? exp2f(s4[t][r] * cexp) : 0.0f;
                p_lds[wave][qd * 4 + r][t * 16 + cc] = f2b(p);
            }
        bf16x8 pf0 = *(const bf16x8*)&p_lds[wave][cc][qd * 8];
        bf16x8 pf1 = *(const bf16x8*)&p_lds[wave][cc][32 + qd * 8];
        lac = mfma16(pf0, ones, lac);
        lac = mfma16(pf1, ones, lac);
#pragma unroll
        for (int g = 0; g < 4; ++g) {
            O4[g] = mfma16(pf0, vf[g][0], O4[g]);
            O4[g] = mfma16(pf1, vf[g][1], O4[g]);
        }
        __syncthreads();               // buf^1 staged AND all waves done with buf
        buf ^= 1;
    }
#undef STAGE

    // wave-private epilogue: O rows qt*16+qd*4+r, cols g*16+cc
    float* op = Opart + (size_t)blk * 4096;
#pragma unroll
    for (int g = 0; g < 4; ++g)
#pragma unroll
        for (int r = 0; r < 4; ++r)
            op[(qt * 16 + qd * 4 + r) * 64 + g * 16 + cc] = O4[g][r];
    if (cc == 0) {
#pragma unroll
        for (int r = 0; r < 4; ++r)
            lpart[blk * 64 + qt * 16 + qd * 4 + r] = lac[r];
    }
}

// ---------------- combine partials + normalize + FF-LayerNorm -> bf16 rows --------
// partial layout: blk = b*32 + h*4 + fs ; Opart[blk][64][64], lpart[blk][64]
__global__ __launch_bounds__(256) void ln_combine(const float* __restrict__ Opart,
                                                  const float* __restrict__ lpart,
                                                  const float* __restrict__ gw,
                                                  const float* __restrict__ bw,
                                                  unsigned short* __restrict__ out) {
    int row = blockIdx.x * 4 + (threadIdx.x >> 6);   // b*64+q
    int lane = threadIdx.x & 63;
    int b = row >> 6, q = row & 63;
    int h = lane >> 3;
    int dh0 = (lane & 7) * 8;
    int blkbase = b * 32 + h * 4;
    float o[8] = {0,0,0,0,0,0,0,0};
    float l = 0.0f;
#pragma unroll
    for (int fsplit = 0; fsplit < 4; ++fsplit) {
        const float* op = Opart + (size_t)(blkbase + fsplit) * 4096 + q * 64 + dh0;
        float4 a0 = *(const float4*)op;
        float4 a1 = *(const float4*)(op + 4);
        o[0] += a0.x; o[1] += a0.y; o[2] += a0.z; o[3] += a0.w;
        o[4] += a1.x; o[5] += a1.y; o[6] += a1.z; o[7] += a1.w;
        l += lpart[(blkbase + fsplit) * 64 + q];
    }
    float inv = (l > 0.0f) ? 1.0f / l : 0.0f;
    float s = 0.0f, sq = 0.0f;
#pragma unroll
    for (int j = 0; j < 8; ++j) { o[j] *= inv; s += o[j]; sq += o[j] * o[j]; }
#pragma unroll
    for (int m = 1; m < 64; m <<= 1) {
        s  += __shfl_xor(s, m);
        sq += __shfl_xor(sq, m);
    }
    float mean = s * (1.0f / 512.0f);
    float var  = sq * (1.0f / 512.0f) - mean * mean;
    float rs   = rsqrtf(var + 1e-5f);
    int d0 = lane * 8;
    float4 g0 = *(const float4*)(gw + d0);
    float4 g1 = *(const float4*)(gw + d0 + 4);
    float4 b0 = *(const float4*)(bw + d0);
    float4 b1 = *(const float4*)(bw + d0 + 4);
    ushort4 w0, w1;
    w0.x = f2b((o[0] - mean) * rs * g0.x + b0.x);
    w0.y = f2b((o[1] - mean) * rs * g0.y + b0.y);
    w0.z = f2b((o[2] - mean) * rs * g0.z + b0.z);
    w0.w = f2b((o[3] - mean) * rs * g0.w + b0.w);
    w1.x = f2b((o[4] - mean) * rs * g1.x + b1.x);
    w1.y = f2b((o[5] - mean) * rs * g1.y + b1.y);
    w1.z = f2b((o[6] - mean) * rs * g1.z + b1.z);
    w1.w = f2b((o[7] - mean) * rs * g1.w + b1.w);
    *(ushort4*)(out + (size_t)row * 512 + d0) = w0;
    *(ushort4*)(out + (size_t)row * 512 + d0 + 4) = w1;
}

// ---------------- host ----------------
extern "C" void kernel_launch(void* const* d_in, const int* in_sizes, int n_in,
                              void* d_out, int out_size, void* d_ws, size_t ws_size,
                              hipStream_t stream) {
    const float* features = (const float*)d_in[0];
    const float* latents  = (const float*)d_in[1];
    const int*   mask     = (const int*)d_in[2];
    const float* gf  = (const float*)d_in[3];
    const float* bf_ = (const float*)d_in[4];
    const float* gl  = (const float*)d_in[5];
    const float* bl  = (const float*)d_in[6];
    const float* Wq  = (const float*)d_in[7];
    const float* Wk  = (const float*)d_in[8];
    const float* Wv  = (const float*)d_in[9];
    const float* gff = (const float*)d_in[10];
    const float* bff = (const float*)d_in[11];
    const float* W1  = (const float*)d_in[12];
    const float* W2  = (const float*)d_in[13];

    char* ws = (char*)d_ws;
    unsigned short* xn   = (unsigned short*)(ws);                    // 64 MB — dead after gemm_kv
    unsigned short* Kbuf = (unsigned short*)(ws + 67108864ull);      // 64 MB head-blocked K
    unsigned short* VTb  = (unsigned short*)(ws + 134217728ull);     // 64 MB head-blocked V^T tiles
    unsigned short* latn = (unsigned short*)(ws + 201326592ull);     // 1 MB
    unsigned short* Qbuf = (unsigned short*)(ws + 202375168ull);     // 1 MB
    unsigned short* ffin = (unsigned short*)(ws + 205520896ull);     // 1 MB
    unsigned short* hbuf = (unsigned short*)(ws + 206569472ull);     // 2 MB
    unsigned short* WqT  = (unsigned short*)(ws + 208666624ull);
    unsigned short* WkT  = (unsigned short*)(ws + 209190912ull);
    unsigned short* WvT  = (unsigned short*)(ws + 209715200ull);
    unsigned short* W1T  = (unsigned short*)(ws + 210239488ull);
    unsigned short* W2T  = (unsigned short*)(ws + 211288064ull);     // 1 MB -> ends 212336640
    int* cidx = (int*)(ws + 212336640ull);                           // 256 KB
    int* cntp = (int*)(ws + 212598784ull);                           // 128 B
    // attention partials reuse xn's region (xn dead once projections finish)
    float* Opart = (float*)(ws);                                     // 512*4096*4 = 8 MB
    float* lpart = (float*)(ws + 8388608ull);                        // 128 KB

    // mask compaction (parallel two-phase ballot + scan)
    mask_compact<<<16, 1024, 0, stream>>>(mask, cidx, cntp);

    // all weight transposes in one launch
    transpose_all<<<1792, 256, 0, stream>>>(Wq, Wk, Wv, W1, W2, WqT, WkT, WvT, W1T, W2T);

    // LayerNorms -> bf16 (features gathered+compacted AND latents, one launch)
    ln_all<<<16640, 256, 0, stream>>>(features, latents, cidx, cntp,
                                      gf, bf_, gl, bl, xn, latn);

    // K / V projection, split: y=0 K-blocks, y=1 V-blocks (m97 shape, 3 blocks/CU)
    gemm_kv<<<dim3(2048, 2), 256, 0, stream>>>(xn, WkT, WvT, cntp, Kbuf, VTb);
    // Qp = latn @ Wq       : (1024,512)  — 128 blocks
    gemm_bt64<0><<<dim3(8, 16), 256, 0, stream>>>(latn, WqT, Qbuf, 1024, 512, 512);

    // fused attention: LDS-double-buffered chunk pipeline, wave = q-tile,
    // 4-way feature split, 3 blocks/CU
    attn_kernel<<<512, 256, 0, stream>>>(Qbuf, Kbuf, VTb, cntp, Opart, lpart);
    ln_combine<<<256, 256, 0, stream>>>(Opart, lpart, gff, bff, ffin);

    // FF: W1 -> relu -> W2   — 256 / 128 blocks
    gemm_bt64<1><<<dim3(16, 16), 256, 0, stream>>>(ffin, W1T, hbuf, 1024, 1024, 512);
    gemm_bt64<2><<<dim3(8, 16), 256, 0, stream>>>(hbuf, W2T, (float*)d_out, 1024, 512, 1024);
}

// Round 7
// 321.252 us; speedup vs baseline: 1.2262x; 1.2262x over previous
//
#include <hip/hip_runtime.h>
#include <hip/hip_bf16.h>
#include <math.h>

// B=16, F=4096, Q=64, DIM=512, H=8, DH=64, MULT=2
typedef short bf16x8 __attribute__((ext_vector_type(8)));
typedef float f32x4 __attribute__((ext_vector_type(4)));

__device__ __forceinline__ f32x4 mfma16(bf16x8 a, bf16x8 b, f32x4 c) {
    return __builtin_amdgcn_mfma_f32_16x16x32_bf16(a, b, c, 0, 0, 0);
}

// manual fp32 -> bf16 round-to-nearest-even (all values finite here)
__device__ __forceinline__ unsigned short f2b(float f) {
    unsigned int x = __float_as_uint(f);
    unsigned int r = (x + 0x7fffu + ((x >> 16) & 1u)) >> 16;
    return (unsigned short)r;
}

#define GLOBAL_AS(p) ((__attribute__((address_space(1))) void*)(p))
#define LDS_AS(p)    ((__attribute__((address_space(3))) void*)(p))

// ---------------- mask compaction: PARALLEL two-phase ballot + LDS scan -----------
__global__ __launch_bounds__(1024) void mask_compact(const int* __restrict__ mask,
                                                     int* __restrict__ cidx,
                                                     int* __restrict__ cntp) {
    __shared__ unsigned long long bals[64];
    __shared__ int base[64];
    int b = blockIdx.x;
    int tid = threadIdx.x;
    int wave = tid >> 6, lane = tid & 63;
    const int* mb = mask + b * 4096;
#pragma unroll
    for (int k = 0; k < 4; ++k) {
        int g = wave * 4 + k;
        int m = mb[g * 64 + lane] != 0;
        unsigned long long bal = __ballot(m);
        if (lane == 0) bals[g] = bal;
    }
    __syncthreads();
    if (wave == 0) {
        int v = __popcll(bals[lane]);
        int own = v;
#pragma unroll
        for (int off = 1; off < 64; off <<= 1) {
            int n = __shfl_up(v, off);
            if (lane >= off) v += n;
        }
        base[lane] = v - own;          // exclusive prefix
        if (lane == 63) {
            cntp[b] = v;
            cntp[16 + b] = (v + 127) & ~127;
        }
    }
    __syncthreads();
#pragma unroll
    for (int k = 0; k < 4; ++k) {
        int g = wave * 4 + k;
        unsigned long long bal = bals[g];
        int m = (int)((bal >> lane) & 1ull);
        int pre = __popcll(bal & ((1ull << lane) - 1ull));
        if (m) cidx[b * 4096 + base[g] + pre] = g * 64 + lane;
    }
}

// ---------------- merged LayerNorm: features (gather+compact) AND latents ---------
// blocks [0,16384): features rows (b*4096+j, gathered); [16384,16640): latent rows.
__global__ __launch_bounds__(256) void ln_all(const float* __restrict__ feat,
                                              const float* __restrict__ lat,
                                              const int* __restrict__ cidx,
                                              const int* __restrict__ cntp,
                                              const float* __restrict__ gf,
                                              const float* __restrict__ bf_,
                                              const float* __restrict__ gl,
                                              const float* __restrict__ bl,
                                              unsigned short* __restrict__ xn,
                                              unsigned short* __restrict__ latn) {
    int bid = blockIdx.x;
    int lane = threadIdx.x & 63;
    const float* rp; unsigned short* orow; const float *gw, *bw;
    if (bid < 16384) {
        int row = bid * 4 + (threadIdx.x >> 6);      // b*4096 + j
        int b = row >> 12, j = row & 4095;
        int cnt = cntp[b], padded = cntp[16 + b];
        if (j >= padded) return;
        orow = xn + (size_t)row * 512;
        if (j >= cnt) {
            ushort4 z; z.x = z.y = z.z = z.w = 0;
            *(ushort4*)(orow + lane * 4) = z;
            *(ushort4*)(orow + 256 + lane * 4) = z;
            return;
        }
        int src = cidx[b * 4096 + j];
        rp = feat + ((size_t)b * 4096 + src) * 512;
        gw = gf; bw = bf_;
    } else {
        int row = (bid - 16384) * 4 + (threadIdx.x >> 6);
        rp = lat + (size_t)row * 512;
        orow = latn + (size_t)row * 512;
        gw = gl; bw = bl;
    }
    float4 x0 = *(const float4*)(rp + lane * 4);
    float4 x1 = *(const float4*)(rp + 256 + lane * 4);
    float s  = x0.x + x0.y + x0.z + x0.w + x1.x + x1.y + x1.z + x1.w;
    float sq = x0.x*x0.x + x0.y*x0.y + x0.z*x0.z + x0.w*x0.w
             + x1.x*x1.x + x1.y*x1.y + x1.z*x1.z + x1.w*x1.w;
#pragma unroll
    for (int m = 1; m < 64; m <<= 1) {
        s  += __shfl_xor(s, m);
        sq += __shfl_xor(sq, m);
    }
    float mean = s * (1.0f / 512.0f);
    float var  = sq * (1.0f / 512.0f) - mean * mean;
    float rs   = rsqrtf(var + 1e-5f);
    float4 g0 = *(const float4*)(gw + lane * 4);
    float4 g1 = *(const float4*)(gw + 256 + lane * 4);
    float4 b0 = *(const float4*)(bw + lane * 4);
    float4 b1 = *(const float4*)(bw + 256 + lane * 4);
    ushort4 o0, o1;
    o0.x = f2b((x0.x - mean) * rs * g0.x + b0.x);
    o0.y = f2b((x0.y - mean) * rs * g0.y + b0.y);
    o0.z = f2b((x0.z - mean) * rs * g0.z + b0.z);
    o0.w = f2b((x0.w - mean) * rs * g0.w + b0.w);
    o1.x = f2b((x1.x - mean) * rs * g1.x + b1.x);
    o1.y = f2b((x1.y - mean) * rs * g1.y + b1.y);
    o1.z = f2b((x1.z - mean) * rs * g1.z + b1.z);
    o1.w = f2b((x1.w - mean) * rs * g1.w + b1.w);
    *(ushort4*)(orow + lane * 4) = o0;
    *(ushort4*)(orow + 256 + lane * 4) = o1;
}

// ---------------- all 5 weight transposes in ONE launch ---------------------------
__global__ __launch_bounds__(256) void transpose_all(const float* __restrict__ Wq,
                                                     const float* __restrict__ Wk,
                                                     const float* __restrict__ Wv,
                                                     const float* __restrict__ W1,
                                                     const float* __restrict__ W2,
                                                     unsigned short* __restrict__ WqT,
                                                     unsigned short* __restrict__ WkT,
                                                     unsigned short* __restrict__ WvT,
                                                     unsigned short* __restrict__ W1T,
                                                     unsigned short* __restrict__ W2T) {
    __shared__ float tile[32][33];
    int id = blockIdx.x;
    const float* in; unsigned short* out; int R, C;
    if (id < 256)       { in = Wq; out = WqT; R = 512;  C = 512;  }
    else if (id < 512)  { in = Wk; out = WkT; R = 512;  C = 512;  id -= 256;  }
    else if (id < 768)  { in = Wv; out = WvT; R = 512;  C = 512;  id -= 512;  }
    else if (id < 1280) { in = W1; out = W1T; R = 512;  C = 1024; id -= 768;  }
    else                { in = W2; out = W2T; R = 1024; C = 512;  id -= 1280; }
    int tilesX = C >> 5;
    int c0 = (id % tilesX) * 32, r0 = (id / tilesX) * 32;
    int tx = threadIdx.x & 31, ty = threadIdx.x >> 5;
#pragma unroll
    for (int i = 0; i < 32; i += 8)
        tile[ty + i][tx] = in[(size_t)(r0 + ty + i) * C + c0 + tx];
    __syncthreads();
#pragma unroll
    for (int i = 0; i < 32; i += 8)
        out[(size_t)(c0 + ty + i) * R + r0 + tx] = f2b(tile[tx][ty + i]);
}

// ---------------- small GEMM, 64x64 tile: C[M,N] = A[M,K] * Bt[N,K]^T --------------
template <int EPI>
__global__ __launch_bounds__(256) void gemm_bt64(const unsigned short* __restrict__ A,
                                                 const unsigned short* __restrict__ Bt,
                                                 void* __restrict__ Cv,
                                                 int M, int N, int K) {
    __shared__ unsigned short As[64 * 32];
    __shared__ unsigned short Bs[64 * 32];
    const int tid = threadIdx.x;
    const int wave = tid >> 6, lane = tid & 63;
    const int qd = lane >> 4, cc = lane & 15;
    const int m0 = blockIdx.y * 64, n0 = blockIdx.x * 64;
    const int wm = (wave >> 1) * 32, wn = (wave & 1) * 32;
    const int lrow = wave * 16 + (lane >> 2);
    const int lcol = (lane & 3) * 8;
    f32x4 acc[2][2] = {};

    for (int kt = 0; kt < K; kt += 32) {
        const unsigned short* ga = A + (size_t)(m0 + lrow) * K + kt + lcol;
        __builtin_amdgcn_global_load_lds(GLOBAL_AS(ga), LDS_AS(&As[wave * 512]), 16, 0, 0);
        const unsigned short* gb = Bt + (size_t)(n0 + lrow) * K + kt + lcol;
        __builtin_amdgcn_global_load_lds(GLOBAL_AS(gb), LDS_AS(&Bs[wave * 512]), 16, 0, 0);
        __syncthreads();
        bf16x8 af[2], bfr[2];
#pragma unroll
        for (int i = 0; i < 2; ++i)
            af[i] = *(const bf16x8*)&As[(wm + i * 16 + cc) * 32 + qd * 8];
#pragma unroll
        for (int j = 0; j < 2; ++j)
            bfr[j] = *(const bf16x8*)&Bs[(wn + j * 16 + cc) * 32 + qd * 8];
#pragma unroll
        for (int i = 0; i < 2; ++i)
#pragma unroll
            for (int j = 0; j < 2; ++j)
                acc[i][j] = mfma16(af[i], bfr[j], acc[i][j]);
        __syncthreads();
    }
#pragma unroll
    for (int i = 0; i < 2; ++i) {
#pragma unroll
        for (int j = 0; j < 2; ++j) {
            int row = m0 + wm + i * 16 + qd * 4;
            int col = n0 + wn + j * 16 + cc;
#pragma unroll
            for (int r = 0; r < 4; ++r) {
                float v = acc[i][j][r];
                if (EPI == 1) v = fmaxf(v, 0.0f);
                if (EPI == 2)
                    ((float*)Cv)[(size_t)(row + r) * N + col] = v;
                else
                    ((unsigned short*)Cv)[(size_t)(row + r) * N + col] = f2b(v);
            }
        }
    }
}

// ---------------- fused K+V projection, LDS-staged COALESCED epilogue --------------
// Fused structure (32 MFMA / 3 global_load_lds per k-step — best barrier
// amortization; the split variant regressed). Epilogue: accumulators -> 32 KB LDS
// stage tile -> 4 KB-contiguous block-wide streams. Fixes the 2x write
// amplification (WRITE_SIZE 267 MB vs 128 MB logical) from 32 B-granule stores.
// Output layouts (unchanged):
//   Khm[b*8+h][f 4096][dh 64]              (a 64-f chunk = 8KB contiguous)
//   Vhm[b*8+h][ftile 64][dh 64][fin 64]    (a 64-f chunk = one 8KB tile)
__global__ __launch_bounds__(256, 2) void gemm_kv(const unsigned short* __restrict__ Xn,
                                                  const unsigned short* __restrict__ WkT,
                                                  const unsigned short* __restrict__ WvT,
                                                  const int* __restrict__ cntp,
                                                  unsigned short* __restrict__ Kout,
                                                  unsigned short* __restrict__ VTout) {
    const int L = blockIdx.x;
    const int t7 = L >> 3;
    const int c = t7 & 3;
    const int m = ((t7 >> 2) << 3) | (L & 7);
    const int m0 = m * 128;
    const int b = m0 >> 12;
    if ((m0 & 4095) >= cntp[16 + b]) return;   // slab fully beyond padded count
    __shared__ unsigned short Xs[128 * 32];
    __shared__ unsigned short Ks[128 * 32];
    __shared__ unsigned short Vs[128 * 32];
    __shared__ unsigned short stage[128 * 128];   // 32 KB epilogue staging
    const int tid = threadIdx.x;
    const int wave = tid >> 6, lane = tid & 63;
    const int qd = lane >> 4, cc = lane & 15;
    const int n0 = c * 128;
    const int wm = (wave >> 1) * 64, wn = (wave & 1) * 64;
    const int lrow = lane >> 2;
    const int lcol = (lane & 3) * 8;
    f32x4 accK[4][4] = {};
    f32x4 accV[4][4] = {};

    for (int kt = 0; kt < 512; kt += 32) {
#pragma unroll
        for (int r = 0; r < 2; ++r) {
            int slab = wave * 16 + r * 64;
            const unsigned short* gx = Xn + (size_t)(m0 + slab + lrow) * 512 + kt + lcol;
            __builtin_amdgcn_global_load_lds(GLOBAL_AS(gx), LDS_AS(&Xs[slab * 32]), 16, 0, 0);
            const unsigned short* gk = WkT + (size_t)(n0 + slab + lrow) * 512 + kt + lcol;
            __builtin_amdgcn_global_load_lds(GLOBAL_AS(gk), LDS_AS(&Ks[slab * 32]), 16, 0, 0);
            const unsigned short* gv = WvT + (size_t)(n0 + slab + lrow) * 512 + kt + lcol;
            __builtin_amdgcn_global_load_lds(GLOBAL_AS(gv), LDS_AS(&Vs[slab * 32]), 16, 0, 0);
        }
        __syncthreads();
        bf16x8 xf[4], kf[4], vf[4];
#pragma unroll
        for (int i = 0; i < 4; ++i)
            xf[i] = *(const bf16x8*)&Xs[(wm + i * 16 + cc) * 32 + qd * 8];
#pragma unroll
        for (int j = 0; j < 4; ++j) {
            kf[j] = *(const bf16x8*)&Ks[(wn + j * 16 + cc) * 32 + qd * 8];
            vf[j] = *(const bf16x8*)&Vs[(wn + j * 16 + cc) * 32 + qd * 8];
        }
#pragma unroll
        for (int i = 0; i < 4; ++i)
#pragma unroll
            for (int j = 0; j < 4; ++j) {
                accK[i][j] = mfma16(xf[i], kf[j], accK[i][j]);    // rows=f, cols=dh
                accV[j][i] = mfma16(vf[j], xf[i], accV[j][i]);    // rows=dh, cols=f
            }
        __syncthreads();
    }
    const int fbase = m0 & 4095;          // f within batch, multiple of 128

    // ---- K: stage[f_loc 128][dhg_loc 128] then stream 2 segs x 16 KB contiguous --
#pragma unroll
    for (int i = 0; i < 4; ++i)
#pragma unroll
        for (int j = 0; j < 4; ++j) {
            int row = wm + i * 16 + qd * 4;       // f local
            int col = wn + j * 16 + cc;           // dh-global local (0..127)
#pragma unroll
            for (int r = 0; r < 4; ++r)
                stage[(row + r) * 128 + col] = f2b(accK[i][j][r]);
        }
    __syncthreads();
#pragma unroll
    for (int s = 0; s < 2; ++s) {
        int hh = (c << 1) | s;                    // heads 2c, 2c+1
        char* gbase = (char*)(Kout + ((size_t)(b * 8 + hh) * 4096 + fbase) * 64);
#pragma unroll
        for (int it = 0; it < 4; ++it) {
            int o = it * 4096 + tid * 16;         // byte offset in 16 KB seg
            int row = o >> 7;                     // f local (128 B per f-row)
            int inb = o & 127;
            *(bf16x8*)(gbase + o) =
                *(const bf16x8*)((const char*)stage + row * 256 + s * 128 + inb);
        }
    }
    __syncthreads();

    // ---- V: stage[d_loc 128][f_loc 128] then 4 regions (head-half, ftile) x 8 KB -
#pragma unroll
    for (int j = 0; j < 4; ++j)
#pragma unroll
        for (int i = 0; i < 4; ++i) {
            int d = wn + j * 16 + qd * 4;         // dh-global local (0..127)
            int fl = wm + i * 16 + cc;            // f local
#pragma unroll
            for (int r = 0; r < 4; ++r)
                stage[(d + r) * 128 + fl] = f2b(accV[j][i][r]);
        }
    __syncthreads();
#pragma unroll
    for (int hs = 0; hs < 2; ++hs)
#pragma unroll
        for (int ft = 0; ft < 2; ++ft) {
            int hh = (c << 1) | hs;
            int ftile = (fbase >> 6) + ft;
            char* gbase = (char*)(VTout + (size_t)(b * 8 + hh) * 262144
                                        + (size_t)ftile * 4096);
#pragma unroll
            for (int it = 0; it < 2; ++it) {
                int o = it * 4096 + tid * 16;     // byte offset in 8 KB region
                int dl = o >> 7;                  // dh within region (0..63)
                int inb = o & 127;
                *(bf16x8*)(gbase + o) =
                    *(const bf16x8*)((const char*)stage + (hs * 64 + dl) * 256
                                     + ft * 128 + inb);
            }
        }
}

// ---------------- fused attention, LDS double-buffered chunk pipeline --------------
// grid = 512: (b, h, fs of 4). Waves SHARE each chunk (wave = q-tile owner qt);
// block walks chunks c = fs, fs+4, ... (~8 chunks) with double-buffered LDS staging
// via global_load_lds (stage c+1 issued before computing c; one barrier per chunk).
// K/V LDS tiles are XOR-swizzled (linear dest + pre-swizzled global source +
// swizzled read) to kill the 16-way stride-128B ds_read_b128 bank conflict.
// Wave-private O accumulation (no cross-wave combine). 18 MFMA/chunk/wave.
__global__ __launch_bounds__(256, 3) void attn_kernel(const unsigned short* __restrict__ Qb,
                                                      const unsigned short* __restrict__ Khm,
                                                      const unsigned short* __restrict__ Vhm,
                                                      const int* __restrict__ cntp,
                                                      float* __restrict__ Opart,
                                                      float* __restrict__ lpart) {
    int blk = blockIdx.x;              // b*32 + h*4 + fs
    int b = blk >> 5;
    int h = (blk >> 2) & 7;
    int fs = blk & 3;
    int cnt = cntp[b];
    int pad = cntp[16 + b];
    int nchunks = pad >> 6;            // 64-f chunks
    int wave = threadIdx.x >> 6, lane = threadIdx.x & 63;
    int qd = lane >> 4, cc = lane & 15;
    const int qt = wave;               // wave owns one 16-q tile

    __shared__ unsigned short Ks[2][64 * 64];     // 2 x 8 KB
    __shared__ unsigned short Vs[2][64 * 64];     // 2 x 8 KB
    __shared__ unsigned short p_lds[4][16][72];   // 9 KB

    const unsigned short* Kbase = Khm + (size_t)(b * 8 + h) * 262144;   // [4096][64]
    const unsigned short* Vbase = Vhm + (size_t)(b * 8 + h) * 262144;   // [64 tiles][64][64]

    // Q fragments for this wave's q-tile (held in registers for the whole kernel)
    const unsigned short* qrow = Qb + (size_t)(b * 64 + qt * 16 + cc) * 512 + h * 64;
    bf16x8 qf0 = *(const bf16x8*)(qrow + qd * 8);
    bf16x8 qf1 = *(const bf16x8*)(qrow + 32 + qd * 8);
    bf16x8 ones;
#pragma unroll
    for (int j = 0; j < 8; ++j) ones[j] = (short)0x3F80;  // bf16 1.0

    f32x4 O4[4] = {};                  // [g]  (dh blocks)
    f32x4 lac = {};
    const float cexp = 0.1803368801f;  // 0.125 * log2(e)

    // stage macro: 16 KB (K 8KB + V 8KB) per chunk; source pre-swizzled so that
    // lds[o] = src[o ^ ((row&7)<<4)], row = o>>7 (involution within each 128B row)
#define STAGE(dst, cidx) do {                                                       \
        const char* kt_ = (const char*)(Kbase + (size_t)(cidx) * 4096);             \
        const char* vt_ = (const char*)(Vbase + (size_t)(cidx) * 4096);             \
        char* kd_ = (char*)&Ks[dst][0];                                             \
        char* vd_ = (char*)&Vs[dst][0];                                             \
        _Pragma("unroll")                                                           \
        for (int i_ = 0; i_ < 2; ++i_) {                                            \
            int o_ = i_ * 4096 + wave * 1024 + lane * 16;                           \
            int sb_ = o_ ^ (((o_ >> 7) & 7) << 4);                                  \
            __builtin_amdgcn_global_load_lds(GLOBAL_AS(kt_ + sb_),                  \
                LDS_AS(kd_ + i_ * 4096 + wave * 1024), 16, 0, 0);                   \
            __builtin_amdgcn_global_load_lds(GLOBAL_AS(vt_ + sb_),                  \
                LDS_AS(vd_ + i_ * 4096 + wave * 1024), 16, 0, 0);                   \
        }                                                                           \
    } while (0)

    int buf = 0;
    if (fs < nchunks) STAGE(0, fs);
    __syncthreads();                   // drains vmcnt -> buf 0 ready

    const int swz = (cc & 7) << 4;
    for (int c = fs; c < nchunks; c += 4) {
        int cn = c + 4;
        if (cn < nchunks) STAGE(buf ^ 1, cn);   // prefetch flies under compute

        const char* ksb = (const char*)&Ks[buf][0];
        const char* vsb = (const char*)&Vs[buf][0];
        int f0 = c * 64;
        bf16x8 kf[4][2], vf[4][2];
        int mv[4];
#pragma unroll
        for (int t = 0; t < 4; ++t) {
            int rb = (t * 16 + cc) * 128;
            kf[t][0] = *(const bf16x8*)(ksb + rb + ((qd << 4) ^ swz));
            kf[t][1] = *(const bf16x8*)(ksb + rb + ((64 + (qd << 4)) ^ swz));
            mv[t] = (f0 + t * 16 + cc) < cnt;
        }
#pragma unroll
        for (int g = 0; g < 4; ++g) {
            int rb = (g * 16 + cc) * 128;
            vf[g][0] = *(const bf16x8*)(vsb + rb + ((qd << 4) ^ swz));
            vf[g][1] = *(const bf16x8*)(vsb + rb + ((64 + (qd << 4)) ^ swz));
        }
        f32x4 s4[4] = {};
#pragma unroll
        for (int t = 0; t < 4; ++t) {
            s4[t] = mfma16(qf0, kf[t][0], s4[t]);
            s4[t] = mfma16(qf1, kf[t][1], s4[t]);
        }
#pragma unroll
        for (int t = 0; t < 4; ++t)
#pragma unroll
            for (int r = 0; r < 4; ++r) {
                float p = mv[t] ? exp2f(s4[t][r] * cexp) : 0.0f;
                p_lds[wave][qd * 4 + r][t * 16 + cc] = f2b(p);
            }
        bf16x8 pf0 = *(const bf16x8*)&p_lds[wave][cc][qd * 8];
        bf16x8 pf1 = *(const bf16x8*)&p_lds[wave][cc][32 + qd * 8];
        lac = mfma16(pf0, ones, lac);
        lac = mfma16(pf1, ones, lac);
#pragma unroll
        for (int g = 0; g < 4; ++g) {
            O4[g] = mfma16(pf0, vf[g][0], O4[g]);
            O4[g] = mfma16(pf1, vf[g][1], O4[g]);
        }
        __syncthreads();               // buf^1 staged AND all waves done with buf
        buf ^= 1;
    }
#undef STAGE

    // wave-private epilogue: O rows qt*16+qd*4+r, cols g*16+cc
    float* op = Opart + (size_t)blk * 4096;
#pragma unroll
    for (int g = 0; g < 4; ++g)
#pragma unroll
        for (int r = 0; r < 4; ++r)
            op[(qt * 16 + qd * 4 + r) * 64 + g * 16 + cc] = O4[g][r];
    if (cc == 0) {
#pragma unroll
        for (int r = 0; r < 4; ++r)
            lpart[blk * 64 + qt * 16 + qd * 4 + r] = lac[r];
    }
}

// ---------------- combine partials + normalize + FF-LayerNorm -> bf16 rows --------
// partial layout: blk = b*32 + h*4 + fs ; Opart[blk][64][64], lpart[blk][64]
__global__ __launch_bounds__(256) void ln_combine(const float* __restrict__ Opart,
                                                  const float* __restrict__ lpart,
                                                  const float* __restrict__ gw,
                                                  const float* __restrict__ bw,
                                                  unsigned short* __restrict__ out) {
    int row = blockIdx.x * 4 + (threadIdx.x >> 6);   // b*64+q
    int lane = threadIdx.x & 63;
    int b = row >> 6, q = row & 63;
    int h = lane >> 3;
    int dh0 = (lane & 7) * 8;
    int blkbase = b * 32 + h * 4;
    float o[8] = {0,0,0,0,0,0,0,0};
    float l = 0.0f;
#pragma unroll
    for (int fsplit = 0; fsplit < 4; ++fsplit) {
        const float* op = Opart + (size_t)(blkbase + fsplit) * 4096 + q * 64 + dh0;
        float4 a0 = *(const float4*)op;
        float4 a1 = *(const float4*)(op + 4);
        o[0] += a0.x; o[1] += a0.y; o[2] += a0.z; o[3] += a0.w;
        o[4] += a1.x; o[5] += a1.y; o[6] += a1.z; o[7] += a1.w;
        l += lpart[(blkbase + fsplit) * 64 + q];
    }
    float inv = (l > 0.0f) ? 1.0f / l : 0.0f;
    float s = 0.0f, sq = 0.0f;
#pragma unroll
    for (int j = 0; j < 8; ++j) { o[j] *= inv; s += o[j]; sq += o[j] * o[j]; }
#pragma unroll
    for (int m = 1; m < 64; m <<= 1) {
        s  += __shfl_xor(s, m);
        sq += __shfl_xor(sq, m);
    }
    float mean = s * (1.0f / 512.0f);
    float var  = sq * (1.0f / 512.0f) - mean * mean;
    float rs   = rsqrtf(var + 1e-5f);
    int d0 = lane * 8;
    float4 g0 = *(const float4*)(gw + d0);
    float4 g1 = *(const float4*)(gw + d0 + 4);
    float4 b0 = *(const float4*)(bw + d0);
    float4 b1 = *(const float4*)(bw + d0 + 4);
    ushort4 w0, w1;
    w0.x = f2b((o[0] - mean) * rs * g0.x + b0.x);
    w0.y = f2b((o[1] - mean) * rs * g0.y + b0.y);
    w0.z = f2b((o[2] - mean) * rs * g0.z + b0.z);
    w0.w = f2b((o[3] - mean) * rs * g0.w + b0.w);
    w1.x = f2b((o[4] - mean) * rs * g1.x + b1.x);
    w1.y = f2b((o[5] - mean) * rs * g1.y + b1.y);
    w1.z = f2b((o[6] - mean) * rs * g1.z + b1.z);
    w1.w = f2b((o[7] - mean) * rs * g1.w + b1.w);
    *(ushort4*)(out + (size_t)row * 512 + d0) = w0;
    *(ushort4*)(out + (size_t)row * 512 + d0 + 4) = w1;
}

// ---------------- host ----------------
extern "C" void kernel_launch(void* const* d_in, const int* in_sizes, int n_in,
                              void* d_out, int out_size, void* d_ws, size_t ws_size,
                              hipStream_t stream) {
    const float* features = (const float*)d_in[0];
    const float* latents  = (const float*)d_in[1];
    const int*   mask     = (const int*)d_in[2];
    const float* gf  = (const float*)d_in[3];
    const float* bf_ = (const float*)d_in[4];
    const float* gl  = (const float*)d_in[5];
    const float* bl  = (const float*)d_in[6];
    const float* Wq  = (const float*)d_in[7];
    const float* Wk  = (const float*)d_in[8];
    const float* Wv  = (const float*)d_in[9];
    const float* gff = (const float*)d_in[10];
    const float* bff = (const float*)d_in[11];
    const float* W1  = (const float*)d_in[12];
    const float* W2  = (const float*)d_in[13];

    char* ws = (char*)d_ws;
    unsigned short* xn   = (unsigned short*)(ws);                    // 64 MB — dead after gemm_kv
    unsigned short* Kbuf = (unsigned short*)(ws + 67108864ull);      // 64 MB head-blocked K
    unsigned short* VTb  = (unsigned short*)(ws + 134217728ull);     // 64 MB head-blocked V^T tiles
    unsigned short* latn = (unsigned short*)(ws + 201326592ull);     // 1 MB
    unsigned short* Qbuf = (unsigned short*)(ws + 202375168ull);     // 1 MB
    unsigned short* ffin = (unsigned short*)(ws + 205520896ull);     // 1 MB
    unsigned short* hbuf = (unsigned short*)(ws + 206569472ull);     // 2 MB
    unsigned short* WqT  = (unsigned short*)(ws + 208666624ull);
    unsigned short* WkT  = (unsigned short*)(ws + 209190912ull);
    unsigned short* WvT  = (unsigned short*)(ws + 209715200ull);
    unsigned short* W1T  = (unsigned short*)(ws + 210239488ull);
    unsigned short* W2T  = (unsigned short*)(ws + 211288064ull);     // 1 MB -> ends 212336640
    int* cidx = (int*)(ws + 212336640ull);                           // 256 KB
    int* cntp = (int*)(ws + 212598784ull);                           // 128 B
    // attention partials reuse xn's region (xn dead once projections finish)
    float* Opart = (float*)(ws);                                     // 512*4096*4 = 8 MB
    float* lpart = (float*)(ws + 8388608ull);                        // 128 KB

    // mask compaction (parallel two-phase ballot + scan)
    mask_compact<<<16, 1024, 0, stream>>>(mask, cidx, cntp);

    // all weight transposes in one launch
    transpose_all<<<1792, 256, 0, stream>>>(Wq, Wk, Wv, W1, W2, WqT, WkT, WvT, W1T, W2T);

    // LayerNorms -> bf16 (features gathered+compacted AND latents, one launch)
    ln_all<<<16640, 256, 0, stream>>>(features, latents, cidx, cntp,
                                      gf, bf_, gl, bl, xn, latn);

    // fused K + V^T projection (coalesced LDS-staged epilogue)
    gemm_kv<<<2048, 256, 0, stream>>>(xn, WkT, WvT, cntp, Kbuf, VTb);
    // Qp = latn @ Wq       : (1024,512)  — 128 blocks
    gemm_bt64<0><<<dim3(8, 16), 256, 0, stream>>>(latn, WqT, Qbuf, 1024, 512, 512);

    // fused attention: LDS-double-buffered chunk pipeline, wave = q-tile,
    // 4-way feature split, 3 blocks/CU
    attn_kernel<<<512, 256, 0, stream>>>(Qbuf, Kbuf, VTb, cntp, Opart, lpart);
    ln_combine<<<256, 256, 0, stream>>>(Opart, lpart, gff, bff, ffin);

    // FF: W1 -> relu -> W2   — 256 / 128 blocks
    gemm_bt64<1><<<dim3(16, 16), 256, 0, stream>>>(ffin, W1T, hbuf, 1024, 1024, 512);
    gemm_bt64<2><<<dim3(8, 16), 256, 0, stream>>>(hbuf, W2T, (float*)d_out, 1024, 512, 1024);
}

// Round 8
// 313.502 us; speedup vs baseline: 1.2565x; 1.0247x over previous
//
#include <hip/hip_runtime.h>
#include <hip/hip_bf16.h>
#include <math.h>

// B=16, F=4096, Q=64, DIM=512, H=8, DH=64, MULT=2
typedef short bf16x8 __attribute__((ext_vector_type(8)));
typedef float f32x4 __attribute__((ext_vector_type(4)));

__device__ __forceinline__ f32x4 mfma16(bf16x8 a, bf16x8 b, f32x4 c) {
    return __builtin_amdgcn_mfma_f32_16x16x32_bf16(a, b, c, 0, 0, 0);
}

// manual fp32 -> bf16 round-to-nearest-even (all values finite here)
__device__ __forceinline__ unsigned short f2b(float f) {
    unsigned int x = __float_as_uint(f);
    unsigned int r = (x + 0x7fffu + ((x >> 16) & 1u)) >> 16;
    return (unsigned short)r;
}

#define GLOBAL_AS(p) ((__attribute__((address_space(1))) void*)(p))
#define LDS_AS(p)    ((__attribute__((address_space(3))) void*)(p))

// ---------------- mask compaction: PARALLEL two-phase ballot + LDS scan -----------
__global__ __launch_bounds__(1024) void mask_compact(const int* __restrict__ mask,
                                                     int* __restrict__ cidx,
                                                     int* __restrict__ cntp) {
    __shared__ unsigned long long bals[64];
    __shared__ int base[64];
    int b = blockIdx.x;
    int tid = threadIdx.x;
    int wave = tid >> 6, lane = tid & 63;
    const int* mb = mask + b * 4096;
#pragma unroll
    for (int k = 0; k < 4; ++k) {
        int g = wave * 4 + k;
        int m = mb[g * 64 + lane] != 0;
        unsigned long long bal = __ballot(m);
        if (lane == 0) bals[g] = bal;
    }
    __syncthreads();
    if (wave == 0) {
        int v = __popcll(bals[lane]);
        int own = v;
#pragma unroll
        for (int off = 1; off < 64; off <<= 1) {
            int n = __shfl_up(v, off);
            if (lane >= off) v += n;
        }
        base[lane] = v - own;          // exclusive prefix
        if (lane == 63) {
            cntp[b] = v;
            cntp[16 + b] = (v + 127) & ~127;
        }
    }
    __syncthreads();
#pragma unroll
    for (int k = 0; k < 4; ++k) {
        int g = wave * 4 + k;
        unsigned long long bal = bals[g];
        int m = (int)((bal >> lane) & 1ull);
        int pre = __popcll(bal & ((1ull << lane) - 1ull));
        if (m) cidx[b * 4096 + base[g] + pre] = g * 64 + lane;
    }
}

// ---------------- merged LayerNorm: features (gather+compact) AND latents ---------
// blocks [0,16384): features rows (b*4096+j, gathered); [16384,16640): latent rows.
__global__ __launch_bounds__(256) void ln_all(const float* __restrict__ feat,
                                              const float* __restrict__ lat,
                                              const int* __restrict__ cidx,
                                              const int* __restrict__ cntp,
                                              const float* __restrict__ gf,
                                              const float* __restrict__ bf_,
                                              const float* __restrict__ gl,
                                              const float* __restrict__ bl,
                                              unsigned short* __restrict__ xn,
                                              unsigned short* __restrict__ latn) {
    int bid = blockIdx.x;
    int lane = threadIdx.x & 63;
    const float* rp; unsigned short* orow; const float *gw, *bw;
    if (bid < 16384) {
        int row = bid * 4 + (threadIdx.x >> 6);      // b*4096 + j
        int b = row >> 12, j = row & 4095;
        int cnt = cntp[b], padded = cntp[16 + b];
        if (j >= padded) return;
        orow = xn + (size_t)row * 512;
        if (j >= cnt) {
            ushort4 z; z.x = z.y = z.z = z.w = 0;
            *(ushort4*)(orow + lane * 4) = z;
            *(ushort4*)(orow + 256 + lane * 4) = z;
            return;
        }
        int src = cidx[b * 4096 + j];
        rp = feat + ((size_t)b * 4096 + src) * 512;
        gw = gf; bw = bf_;
    } else {
        int row = (bid - 16384) * 4 + (threadIdx.x >> 6);
        rp = lat + (size_t)row * 512;
        orow = latn + (size_t)row * 512;
        gw = gl; bw = bl;
    }
    float4 x0 = *(const float4*)(rp + lane * 4);
    float4 x1 = *(const float4*)(rp + 256 + lane * 4);
    float s  = x0.x + x0.y + x0.z + x0.w + x1.x + x1.y + x1.z + x1.w;
    float sq = x0.x*x0.x + x0.y*x0.y + x0.z*x0.z + x0.w*x0.w
             + x1.x*x1.x + x1.y*x1.y + x1.z*x1.z + x1.w*x1.w;
#pragma unroll
    for (int m = 1; m < 64; m <<= 1) {
        s  += __shfl_xor(s, m);
        sq += __shfl_xor(sq, m);
    }
    float mean = s * (1.0f / 512.0f);
    float var  = sq * (1.0f / 512.0f) - mean * mean;
    float rs   = rsqrtf(var + 1e-5f);
    float4 g0 = *(const float4*)(gw + lane * 4);
    float4 g1 = *(const float4*)(gw + 256 + lane * 4);
    float4 b0 = *(const float4*)(bw + lane * 4);
    float4 b1 = *(const float4*)(bw + 256 + lane * 4);
    ushort4 o0, o1;
    o0.x = f2b((x0.x - mean) * rs * g0.x + b0.x);
    o0.y = f2b((x0.y - mean) * rs * g0.y + b0.y);
    o0.z = f2b((x0.z - mean) * rs * g0.z + b0.z);
    o0.w = f2b((x0.w - mean) * rs * g0.w + b0.w);
    o1.x = f2b((x1.x - mean) * rs * g1.x + b1.x);
    o1.y = f2b((x1.y - mean) * rs * g1.y + b1.y);
    o1.z = f2b((x1.z - mean) * rs * g1.z + b1.z);
    o1.w = f2b((x1.w - mean) * rs * g1.w + b1.w);
    *(ushort4*)(orow + lane * 4) = o0;
    *(ushort4*)(orow + 256 + lane * 4) = o1;
}

// ---------------- all 5 weight transposes in ONE launch ---------------------------
__global__ __launch_bounds__(256) void transpose_all(const float* __restrict__ Wq,
                                                     const float* __restrict__ Wk,
                                                     const float* __restrict__ Wv,
                                                     const float* __restrict__ W1,
                                                     const float* __restrict__ W2,
                                                     unsigned short* __restrict__ WqT,
                                                     unsigned short* __restrict__ WkT,
                                                     unsigned short* __restrict__ WvT,
                                                     unsigned short* __restrict__ W1T,
                                                     unsigned short* __restrict__ W2T) {
    __shared__ float tile[32][33];
    int id = blockIdx.x;
    const float* in; unsigned short* out; int R, C;
    if (id < 256)       { in = Wq; out = WqT; R = 512;  C = 512;  }
    else if (id < 512)  { in = Wk; out = WkT; R = 512;  C = 512;  id -= 256;  }
    else if (id < 768)  { in = Wv; out = WvT; R = 512;  C = 512;  id -= 512;  }
    else if (id < 1280) { in = W1; out = W1T; R = 512;  C = 1024; id -= 768;  }
    else                { in = W2; out = W2T; R = 1024; C = 512;  id -= 1280; }
    int tilesX = C >> 5;
    int c0 = (id % tilesX) * 32, r0 = (id / tilesX) * 32;
    int tx = threadIdx.x & 31, ty = threadIdx.x >> 5;
#pragma unroll
    for (int i = 0; i < 32; i += 8)
        tile[ty + i][tx] = in[(size_t)(r0 + ty + i) * C + c0 + tx];
    __syncthreads();
#pragma unroll
    for (int i = 0; i < 32; i += 8)
        out[(size_t)(c0 + ty + i) * R + r0 + tx] = f2b(tile[tx][ty + i]);
}

// ---------------- small GEMM, 64x64 tile, DOUBLE-BUFFERED staging -----------------
// Prefetch k-step t+1 before computing t; ONE barrier per k-step (was 2 with the
// load latency fully exposed at the vmcnt(0) drain).
template <int EPI>
__global__ __launch_bounds__(256) void gemm_bt64(const unsigned short* __restrict__ A,
                                                 const unsigned short* __restrict__ Bt,
                                                 void* __restrict__ Cv,
                                                 int M, int N, int K) {
    __shared__ unsigned short As[2][64 * 32];
    __shared__ unsigned short Bs[2][64 * 32];
    const int tid = threadIdx.x;
    const int wave = tid >> 6, lane = tid & 63;
    const int qd = lane >> 4, cc = lane & 15;
    const int m0 = blockIdx.y * 64, n0 = blockIdx.x * 64;
    const int wm = (wave >> 1) * 32, wn = (wave & 1) * 32;
    const int lrow = wave * 16 + (lane >> 2);
    const int lcol = (lane & 3) * 8;
    f32x4 acc[2][2] = {};

    auto stage = [&](int dst, int kt) {
        const unsigned short* ga = A + (size_t)(m0 + lrow) * K + kt + lcol;
        __builtin_amdgcn_global_load_lds(GLOBAL_AS(ga), LDS_AS(&As[dst][wave * 512]), 16, 0, 0);
        const unsigned short* gb = Bt + (size_t)(n0 + lrow) * K + kt + lcol;
        __builtin_amdgcn_global_load_lds(GLOBAL_AS(gb), LDS_AS(&Bs[dst][wave * 512]), 16, 0, 0);
    };

    int buf = 0;
    stage(0, 0);
    __syncthreads();
    for (int kt = 0; kt < K; kt += 32) {
        if (kt + 32 < K) stage(buf ^ 1, kt + 32);
        bf16x8 af[2], bfr[2];
#pragma unroll
        for (int i = 0; i < 2; ++i)
            af[i] = *(const bf16x8*)&As[buf][(wm + i * 16 + cc) * 32 + qd * 8];
#pragma unroll
        for (int j = 0; j < 2; ++j)
            bfr[j] = *(const bf16x8*)&Bs[buf][(wn + j * 16 + cc) * 32 + qd * 8];
#pragma unroll
        for (int i = 0; i < 2; ++i)
#pragma unroll
            for (int j = 0; j < 2; ++j)
                acc[i][j] = mfma16(af[i], bfr[j], acc[i][j]);
        __syncthreads();               // drains prefetch; all waves done with buf
        buf ^= 1;
    }
#pragma unroll
    for (int i = 0; i < 2; ++i) {
#pragma unroll
        for (int j = 0; j < 2; ++j) {
            int row = m0 + wm + i * 16 + qd * 4;
            int col = n0 + wn + j * 16 + cc;
#pragma unroll
            for (int r = 0; r < 4; ++r) {
                float v = acc[i][j][r];
                if (EPI == 1) v = fmaxf(v, 0.0f);
                if (EPI == 2)
                    ((float*)Cv)[(size_t)(row + r) * N + col] = v;
                else
                    ((unsigned short*)Cv)[(size_t)(row + r) * N + col] = f2b(v);
            }
        }
    }
}

// ---------------- fused K+V projection, dbuf staging + coalesced epilogue ----------
// Fused structure (32 MFMA per k-step). NEW: double-buffered X/K/V LDS staging —
// prefetch k-step t+1 before computing t, one barrier per step (was: issue+drain
// every step, MfmaUtil 10%). LDS 48+32=80 KB -> 2 blocks/CU (unchanged).
// Epilogue: accumulators -> 32 KB LDS stage -> 4 KB-contiguous streams (fixes the
// 2x write amplification). Output layouts:
//   Khm[b*8+h][f 4096][dh 64]              (a 64-f chunk = 8KB contiguous)
//   Vhm[b*8+h][ftile 64][dh 64][fin 64]    (a 64-f chunk = one 8KB tile)
__global__ __launch_bounds__(256, 2) void gemm_kv(const unsigned short* __restrict__ Xn,
                                                  const unsigned short* __restrict__ WkT,
                                                  const unsigned short* __restrict__ WvT,
                                                  const int* __restrict__ cntp,
                                                  unsigned short* __restrict__ Kout,
                                                  unsigned short* __restrict__ VTout) {
    const int L = blockIdx.x;
    const int t7 = L >> 3;
    const int c = t7 & 3;
    const int m = ((t7 >> 2) << 3) | (L & 7);
    const int m0 = m * 128;
    const int b = m0 >> 12;
    if ((m0 & 4095) >= cntp[16 + b]) return;   // slab fully beyond padded count
    __shared__ unsigned short Xs[2][128 * 32];
    __shared__ unsigned short Ks[2][128 * 32];
    __shared__ unsigned short Vs[2][128 * 32];
    __shared__ unsigned short stage[128 * 128];   // 32 KB epilogue staging
    const int tid = threadIdx.x;
    const int wave = tid >> 6, lane = tid & 63;
    const int qd = lane >> 4, cc = lane & 15;
    const int n0 = c * 128;
    const int wm = (wave >> 1) * 64, wn = (wave & 1) * 64;
    const int lrow = lane >> 2;
    const int lcol = (lane & 3) * 8;
    f32x4 accK[4][4] = {};
    f32x4 accV[4][4] = {};

    auto kvstage = [&](int dst, int kt) {
#pragma unroll
        for (int r = 0; r < 2; ++r) {
            int slab = wave * 16 + r * 64;
            const unsigned short* gx = Xn + (size_t)(m0 + slab + lrow) * 512 + kt + lcol;
            __builtin_amdgcn_global_load_lds(GLOBAL_AS(gx), LDS_AS(&Xs[dst][slab * 32]), 16, 0, 0);
            const unsigned short* gk = WkT + (size_t)(n0 + slab + lrow) * 512 + kt + lcol;
            __builtin_amdgcn_global_load_lds(GLOBAL_AS(gk), LDS_AS(&Ks[dst][slab * 32]), 16, 0, 0);
            const unsigned short* gv = WvT + (size_t)(n0 + slab + lrow) * 512 + kt + lcol;
            __builtin_amdgcn_global_load_lds(GLOBAL_AS(gv), LDS_AS(&Vs[dst][slab * 32]), 16, 0, 0);
        }
    };

    int buf = 0;
    kvstage(0, 0);
    __syncthreads();
    for (int kt = 0; kt < 512; kt += 32) {
        if (kt + 32 < 512) kvstage(buf ^ 1, kt + 32);   // prefetch under compute
        bf16x8 xf[4], kf[4], vf[4];
#pragma unroll
        for (int i = 0; i < 4; ++i)
            xf[i] = *(const bf16x8*)&Xs[buf][(wm + i * 16 + cc) * 32 + qd * 8];
#pragma unroll
        for (int j = 0; j < 4; ++j) {
            kf[j] = *(const bf16x8*)&Ks[buf][(wn + j * 16 + cc) * 32 + qd * 8];
            vf[j] = *(const bf16x8*)&Vs[buf][(wn + j * 16 + cc) * 32 + qd * 8];
        }
#pragma unroll
        for (int i = 0; i < 4; ++i)
#pragma unroll
            for (int j = 0; j < 4; ++j) {
                accK[i][j] = mfma16(xf[i], kf[j], accK[i][j]);    // rows=f, cols=dh
                accV[j][i] = mfma16(vf[j], xf[i], accV[j][i]);    // rows=dh, cols=f
            }
        __syncthreads();               // drains prefetch; all waves done with buf
        buf ^= 1;
    }
    const int fbase = m0 & 4095;          // f within batch, multiple of 128

    // ---- K: stage[f_loc 128][dhg_loc 128] then stream 2 segs x 16 KB contiguous --
#pragma unroll
    for (int i = 0; i < 4; ++i)
#pragma unroll
        for (int j = 0; j < 4; ++j) {
            int row = wm + i * 16 + qd * 4;       // f local
            int col = wn + j * 16 + cc;           // dh-global local (0..127)
#pragma unroll
            for (int r = 0; r < 4; ++r)
                stage[(row + r) * 128 + col] = f2b(accK[i][j][r]);
        }
    __syncthreads();
#pragma unroll
    for (int s = 0; s < 2; ++s) {
        int hh = (c << 1) | s;                    // heads 2c, 2c+1
        char* gbase = (char*)(Kout + ((size_t)(b * 8 + hh) * 4096 + fbase) * 64);
#pragma unroll
        for (int it = 0; it < 4; ++it) {
            int o = it * 4096 + tid * 16;         // byte offset in 16 KB seg
            int row = o >> 7;                     // f local (128 B per f-row)
            int inb = o & 127;
            *(bf16x8*)(gbase + o) =
                *(const bf16x8*)((const char*)stage + row * 256 + s * 128 + inb);
        }
    }
    __syncthreads();

    // ---- V: stage[d_loc 128][f_loc 128] then 4 regions (head-half, ftile) x 8 KB -
#pragma unroll
    for (int j = 0; j < 4; ++j)
#pragma unroll
        for (int i = 0; i < 4; ++i) {
            int d = wn + j * 16 + qd * 4;         // dh-global local (0..127)
            int fl = wm + i * 16 + cc;            // f local
#pragma unroll
            for (int r = 0; r < 4; ++r)
                stage[(d + r) * 128 + fl] = f2b(accV[j][i][r]);
        }
    __syncthreads();
#pragma unroll
    for (int hs = 0; hs < 2; ++hs)
#pragma unroll
        for (int ft = 0; ft < 2; ++ft) {
            int hh = (c << 1) | hs;
            int ftile = (fbase >> 6) + ft;
            char* gbase = (char*)(VTout + (size_t)(b * 8 + hh) * 262144
                                        + (size_t)ftile * 4096);
#pragma unroll
            for (int it = 0; it < 2; ++it) {
                int o = it * 4096 + tid * 16;     // byte offset in 8 KB region
                int dl = o >> 7;                  // dh within region (0..63)
                int inb = o & 127;
                *(bf16x8*)(gbase + o) =
                    *(const bf16x8*)((const char*)stage + (hs * 64 + dl) * 256
                                     + ft * 128 + inb);
            }
        }
}

// ---------------- fused attention, LDS double-buffered chunk pipeline --------------
// grid = 512: (b, h, fs of 4). Waves SHARE each chunk (wave = q-tile owner qt);
// block walks chunks c = fs, fs+4, ... (~8 chunks) with double-buffered LDS staging
// via global_load_lds (stage c+1 issued before computing c; one barrier per chunk).
// K/V LDS tiles are XOR-swizzled (linear dest + pre-swizzled global source +
// swizzled read) to kill the 16-way stride-128B ds_read_b128 bank conflict.
// Wave-private O accumulation (no cross-wave combine). 18 MFMA/chunk/wave.
__global__ __launch_bounds__(256, 3) void attn_kernel(const unsigned short* __restrict__ Qb,
                                                      const unsigned short* __restrict__ Khm,
                                                      const unsigned short* __restrict__ Vhm,
                                                      const int* __restrict__ cntp,
                                                      float* __restrict__ Opart,
                                                      float* __restrict__ lpart) {
    int blk = blockIdx.x;              // b*32 + h*4 + fs
    int b = blk >> 5;
    int h = (blk >> 2) & 7;
    int fs = blk & 3;
    int cnt = cntp[b];
    int pad = cntp[16 + b];
    int nchunks = pad >> 6;            // 64-f chunks
    int wave = threadIdx.x >> 6, lane = threadIdx.x & 63;
    int qd = lane >> 4, cc = lane & 15;
    const int qt = wave;               // wave owns one 16-q tile

    __shared__ unsigned short Ks[2][64 * 64];     // 2 x 8 KB
    __shared__ unsigned short Vs[2][64 * 64];     // 2 x 8 KB
    __shared__ unsigned short p_lds[4][16][72];   // 9 KB

    const unsigned short* Kbase = Khm + (size_t)(b * 8 + h) * 262144;   // [4096][64]
    const unsigned short* Vbase = Vhm + (size_t)(b * 8 + h) * 262144;   // [64 tiles][64][64]

    // Q fragments for this wave's q-tile (held in registers for the whole kernel)
    const unsigned short* qrow = Qb + (size_t)(b * 64 + qt * 16 + cc) * 512 + h * 64;
    bf16x8 qf0 = *(const bf16x8*)(qrow + qd * 8);
    bf16x8 qf1 = *(const bf16x8*)(qrow + 32 + qd * 8);
    bf16x8 ones;
#pragma unroll
    for (int j = 0; j < 8; ++j) ones[j] = (short)0x3F80;  // bf16 1.0

    f32x4 O4[4] = {};                  // [g]  (dh blocks)
    f32x4 lac = {};
    const float cexp = 0.1803368801f;  // 0.125 * log2(e)

    // stage macro: 16 KB (K 8KB + V 8KB) per chunk; source pre-swizzled so that
    // lds[o] = src[o ^ ((row&7)<<4)], row = o>>7 (involution within each 128B row)
#define STAGE(dst, cidx) do {                                                       \
        const char* kt_ = (const char*)(Kbase + (size_t)(cidx) * 4096);             \
        const char* vt_ = (const char*)(Vbase + (size_t)(cidx) * 4096);             \
        char* kd_ = (char*)&Ks[dst][0];                                             \
        char* vd_ = (char*)&Vs[dst][0];                                             \
        _Pragma("unroll")                                                           \
        for (int i_ = 0; i_ < 2; ++i_) {                                            \
            int o_ = i_ * 4096 + wave * 1024 + lane * 16;                           \
            int sb_ = o_ ^ (((o_ >> 7) & 7) << 4);                                  \
            __builtin_amdgcn_global_load_lds(GLOBAL_AS(kt_ + sb_),                  \
                LDS_AS(kd_ + i_ * 4096 + wave * 1024), 16, 0, 0);                   \
            __builtin_amdgcn_global_load_lds(GLOBAL_AS(vt_ + sb_),                  \
                LDS_AS(vd_ + i_ * 4096 + wave * 1024), 16, 0, 0);                   \
        }                                                                           \
    } while (0)

    int buf = 0;
    if (fs < nchunks) STAGE(0, fs);
    __syncthreads();                   // drains vmcnt -> buf 0 ready

    const int swz = (cc & 7) << 4;
    for (int c = fs; c < nchunks; c += 4) {
        int cn = c + 4;
        if (cn < nchunks) STAGE(buf ^ 1, cn);   // prefetch flies under compute

        const char* ksb = (const char*)&Ks[buf][0];
        const char* vsb = (const char*)&Vs[buf][0];
        int f0 = c * 64;
        bf16x8 kf[4][2], vf[4][2];
        int mv[4];
#pragma unroll
        for (int t = 0; t < 4; ++t) {
            int rb = (t * 16 + cc) * 128;
            kf[t][0] = *(const bf16x8*)(ksb + rb + ((qd << 4) ^ swz));
            kf[t][1] = *(const bf16x8*)(ksb + rb + ((64 + (qd << 4)) ^ swz));
            mv[t] = (f0 + t * 16 + cc) < cnt;
        }
#pragma unroll
        for (int g = 0; g < 4; ++g) {
            int rb = (g * 16 + cc) * 128;
            vf[g][0] = *(const bf16x8*)(vsb + rb + ((qd << 4) ^ swz));
            vf[g][1] = *(const bf16x8*)(vsb + rb + ((64 + (qd << 4)) ^ swz));
        }
        f32x4 s4[4] = {};
#pragma unroll
        for (int t = 0; t < 4; ++t) {
            s4[t] = mfma16(qf0, kf[t][0], s4[t]);
            s4[t] = mfma16(qf1, kf[t][1], s4[t]);
        }
#pragma unroll
        for (int t = 0; t < 4; ++t)
#pragma unroll
            for (int r = 0; r < 4; ++r) {
                float p = mv[t] ? exp2f(s4[t][r] * cexp) : 0.0f;
                p_lds[wave][qd * 4 + r][t * 16 + cc] = f2b(p);
            }
        bf16x8 pf0 = *(const bf16x8*)&p_lds[wave][cc][qd * 8];
        bf16x8 pf1 = *(const bf16x8*)&p_lds[wave][cc][32 + qd * 8];
        lac = mfma16(pf0, ones, lac);
        lac = mfma16(pf1, ones, lac);
#pragma unroll
        for (int g = 0; g < 4; ++g) {
            O4[g] = mfma16(pf0, vf[g][0], O4[g]);
            O4[g] = mfma16(pf1, vf[g][1], O4[g]);
        }
        __syncthreads();               // buf^1 staged AND all waves done with buf
        buf ^= 1;
    }
#undef STAGE

    // wave-private epilogue: O rows qt*16+qd*4+r, cols g*16+cc
    float* op = Opart + (size_t)blk * 4096;
#pragma unroll
    for (int g = 0; g < 4; ++g)
#pragma unroll
        for (int r = 0; r < 4; ++r)
            op[(qt * 16 + qd * 4 + r) * 64 + g * 16 + cc] = O4[g][r];
    if (cc == 0) {
#pragma unroll
        for (int r = 0; r < 4; ++r)
            lpart[blk * 64 + qt * 16 + qd * 4 + r] = lac[r];
    }
}

// ---------------- combine partials + normalize + FF-LayerNorm -> bf16 rows --------
// partial layout: blk = b*32 + h*4 + fs ; Opart[blk][64][64], lpart[blk][64]
__global__ __launch_bounds__(256) void ln_combine(const float* __restrict__ Opart,
                                                  const float* __restrict__ lpart,
                                                  const float* __restrict__ gw,
                                                  const float* __restrict__ bw,
                                                  unsigned short* __restrict__ out) {
    int row = blockIdx.x * 4 + (threadIdx.x >> 6);   // b*64+q
    int lane = threadIdx.x & 63;
    int b = row >> 6, q = row & 63;
    int h = lane >> 3;
    int dh0 = (lane & 7) * 8;
    int blkbase = b * 32 + h * 4;
    float o[8] = {0,0,0,0,0,0,0,0};
    float l = 0.0f;
#pragma unroll
    for (int fsplit = 0; fsplit < 4; ++fsplit) {
        const float* op = Opart + (size_t)(blkbase + fsplit) * 4096 + q * 64 + dh0;
        float4 a0 = *(const float4*)op;
        float4 a1 = *(const float4*)(op + 4);
        o[0] += a0.x; o[1] += a0.y; o[2] += a0.z; o[3] += a0.w;
        o[4] += a1.x; o[5] += a1.y; o[6] += a1.z; o[7] += a1.w;
        l += lpart[(blkbase + fsplit) * 64 + q];
    }
    float inv = (l > 0.0f) ? 1.0f / l : 0.0f;
    float s = 0.0f, sq = 0.0f;
#pragma unroll
    for (int j = 0; j < 8; ++j) { o[j] *= inv; s += o[j]; sq += o[j] * o[j]; }
#pragma unroll
    for (int m = 1; m < 64; m <<= 1) {
        s  += __shfl_xor(s, m);
        sq += __shfl_xor(sq, m);
    }
    float mean = s * (1.0f / 512.0f);
    float var  = sq * (1.0f / 512.0f) - mean * mean;
    float rs   = rsqrtf(var + 1e-5f);
    int d0 = lane * 8;
    float4 g0 = *(const float4*)(gw + d0);
    float4 g1 = *(const float4*)(gw + d0 + 4);
    float4 b0 = *(const float4*)(bw + d0);
    float4 b1 = *(const float4*)(bw + d0 + 4);
    ushort4 w0, w1;
    w0.x = f2b((o[0] - mean) * rs * g0.x + b0.x);
    w0.y = f2b((o[1] - mean) * rs * g0.y + b0.y);
    w0.z = f2b((o[2] - mean) * rs * g0.z + b0.z);
    w0.w = f2b((o[3] - mean) * rs * g0.w + b0.w);
    w1.x = f2b((o[4] - mean) * rs * g1.x + b1.x);
    w1.y = f2b((o[5] - mean) * rs * g1.y + b1.y);
    w1.z = f2b((o[6] - mean) * rs * g1.z + b1.z);
    w1.w = f2b((o[7] - mean) * rs * g1.w + b1.w);
    *(ushort4*)(out + (size_t)row * 512 + d0) = w0;
    *(ushort4*)(out + (size_t)row * 512 + d0 + 4) = w1;
}

// ---------------- host ----------------
extern "C" void kernel_launch(void* const* d_in, const int* in_sizes, int n_in,
                              void* d_out, int out_size, void* d_ws, size_t ws_size,
                              hipStream_t stream) {
    const float* features = (const float*)d_in[0];
    const float* latents  = (const float*)d_in[1];
    const int*   mask     = (const int*)d_in[2];
    const float* gf  = (const float*)d_in[3];
    const float* bf_ = (const float*)d_in[4];
    const float* gl  = (const float*)d_in[5];
    const float* bl  = (const float*)d_in[6];
    const float* Wq  = (const float*)d_in[7];
    const float* Wk  = (const float*)d_in[8];
    const float* Wv  = (const float*)d_in[9];
    const float* gff = (const float*)d_in[10];
    const float* bff = (const float*)d_in[11];
    const float* W1  = (const float*)d_in[12];
    const float* W2  = (const float*)d_in[13];

    char* ws = (char*)d_ws;
    unsigned short* xn   = (unsigned short*)(ws);                    // 64 MB — dead after gemm_kv
    unsigned short* Kbuf = (unsigned short*)(ws + 67108864ull);      // 64 MB head-blocked K
    unsigned short* VTb  = (unsigned short*)(ws + 134217728ull);     // 64 MB head-blocked V^T tiles
    unsigned short* latn = (unsigned short*)(ws + 201326592ull);     // 1 MB
    unsigned short* Qbuf = (unsigned short*)(ws + 202375168ull);     // 1 MB
    unsigned short* ffin = (unsigned short*)(ws + 205520896ull);     // 1 MB
    unsigned short* hbuf = (unsigned short*)(ws + 206569472ull);     // 2 MB
    unsigned short* WqT  = (unsigned short*)(ws + 208666624ull);
    unsigned short* WkT  = (unsigned short*)(ws + 209190912ull);
    unsigned short* WvT  = (unsigned short*)(ws + 209715200ull);
    unsigned short* W1T  = (unsigned short*)(ws + 210239488ull);
    unsigned short* W2T  = (unsigned short*)(ws + 211288064ull);     // 1 MB -> ends 212336640
    int* cidx = (int*)(ws + 212336640ull);                           // 256 KB
    int* cntp = (int*)(ws + 212598784ull);                           // 128 B
    // attention partials reuse xn's region (xn dead once projections finish)
    float* Opart = (float*)(ws);                                     // 512*4096*4 = 8 MB
    float* lpart = (float*)(ws + 8388608ull);                        // 128 KB

    // mask compaction (parallel two-phase ballot + scan)
    mask_compact<<<16, 1024, 0, stream>>>(mask, cidx, cntp);

    // all weight transposes in one launch
    transpose_all<<<1792, 256, 0, stream>>>(Wq, Wk, Wv, W1, W2, WqT, WkT, WvT, W1T, W2T);

    // LayerNorms -> bf16 (features gathered+compacted AND latents, one launch)
    ln_all<<<16640, 256, 0, stream>>>(features, latents, cidx, cntp,
                                      gf, bf_, gl, bl, xn, latn);

    // fused K + V^T projection (double-buffered staging, coalesced epilogue)
    gemm_kv<<<2048, 256, 0, stream>>>(xn, WkT, WvT, cntp, Kbuf, VTb);
    // Qp = latn @ Wq       : (1024,512)  — 128 blocks
    gemm_bt64<0><<<dim3(8, 16), 256, 0, stream>>>(latn, WqT, Qbuf, 1024, 512, 512);

    // fused attention: LDS-double-buffered chunk pipeline, wave = q-tile,
    // 4-way feature split, 3 blocks/CU
    attn_kernel<<<512, 256, 0, stream>>>(Qbuf, Kbuf, VTb, cntp, Opart, lpart);
    ln_combine<<<256, 256, 0, stream>>>(Opart, lpart, gff, bff, ffin);

    // FF: W1 -> relu -> W2   — 256 / 128 blocks
    gemm_bt64<1><<<dim3(16, 16), 256, 0, stream>>>(ffin, W1T, hbuf, 1024, 1024, 512);
    gemm_bt64<2><<<dim3(8, 16), 256, 0, stream>>>(hbuf, W2T, (float*)d_out, 1024, 512, 1024);
}